// Round 9
// baseline (31.517 us; speedup 1.0000x reference)
//
#include <hip/hip_runtime.h>
#include <hip/hip_bf16.h>

#define B_TOTAL 2048
#define IN_SZ   288
#define GH      64
#define E_NUM   8
#define OUT_N   256
#define NKT     9                 // k-tiles of 32 per expert

#define W2F_BLKS 72               // one (e,kt) slab each
#define ZG_BLKS  32               // 4 waves x 16 rows each

typedef __attribute__((ext_vector_type(8))) short bf16x8;
typedef __attribute__((ext_vector_type(4))) float f32x4;

__device__ __forceinline__ float elu_f(float x) {
    return x > 0.0f ? x : (expf(x) - 1.0f);
}
__device__ __forceinline__ ushort f2bf(float f) {
    __hip_bfloat16 h = __float2bfloat16(f);
    return *reinterpret_cast<ushort*>(&h);
}

// ================= k1: w2 fragments + fused zf-build/gate =================
// blocks [0,72):  w2 -> w2f frag (e,nt,kt): lane l 16B = cols nt*16+(l&15), k kt*32+(l>>4)*8..+7
// blocks [72,104): per wave (16 rows): build zf frags (kept in regs) -> gate MLP
//                  (weight frags gathered from L2) -> softmax -> coefT[e][b]
__global__ __launch_bounds__(256) void prep_kernel(
    const float* __restrict__ w2, const float* __restrict__ z,
    const float* __restrict__ g0_w, const float* __restrict__ g0_b,
    const float* __restrict__ g1_w, const float* __restrict__ g1_b,
    const float* __restrict__ g2_w, const float* __restrict__ g2_b,
    ushort* __restrict__ w2f, ushort* __restrict__ zf, float* __restrict__ coefT)
{
    __shared__ char smem[33536];
    const int t = threadIdx.x;
    const int wid = t >> 6, l = t & 63;
    const int fr = l & 15, fg = l >> 4;

    if (blockIdx.x < W2F_BLKS) {
        // ---- w2 fragment transpose (r7/r8-validated) ----
        float (*ts)[260] = (float(*)[260])smem;
        const int e  = blockIdx.x / NKT;
        const int kt = blockIdx.x - e * NKT;
        const float* src = w2 + ((size_t)e * IN_SZ + kt * 32) * OUT_N;
        #pragma unroll
        for (int q = t; q < 2048; q += 256) {            // 32 rows x 64 float4
            int r = q >> 6, c4 = q & 63;
            *(float4*)&ts[r][c4 * 4] = *(const float4*)(src + (size_t)r * OUT_N + c4 * 4);
        }
        __syncthreads();
        #pragma unroll
        for (int it = 0; it < 4; ++it) {
            int q = t + it * 256;
            int nt = q >> 6, ll = q & 63;
            int qfr = ll & 15, qfg = ll >> 4;
            ushort4 u0, u1;
            u0.x = f2bf(ts[qfg * 8 + 0][nt * 16 + qfr]);
            u0.y = f2bf(ts[qfg * 8 + 1][nt * 16 + qfr]);
            u0.z = f2bf(ts[qfg * 8 + 2][nt * 16 + qfr]);
            u0.w = f2bf(ts[qfg * 8 + 3][nt * 16 + qfr]);
            u1.x = f2bf(ts[qfg * 8 + 4][nt * 16 + qfr]);
            u1.y = f2bf(ts[qfg * 8 + 5][nt * 16 + qfr]);
            u1.z = f2bf(ts[qfg * 8 + 6][nt * 16 + qfr]);
            u1.w = f2bf(ts[qfg * 8 + 7][nt * 16 + qfr]);
            size_t off = ((size_t)((e * 16 + nt) * NKT + kt)) * 512 + ll * 8;
            *(ushort4*)&w2f[off]     = u0;
            *(ushort4*)&w2f[off + 4] = u1;
        }
        return;
    }

    // ---- fused zf + gate: wave wid handles rows mt*16..+15 ----
    ushort (*hscr)[72] = (ushort(*)[72])(smem + wid * 2304);            // [16][72]
    float  (*lgs)[8]   = (float(*)[8])(smem + 4 * 2304 + wid * 512);    // [16][8]

    const int mt = (blockIdx.x - W2F_BLKS) * 4 + wid;   // 0..127
    const int m0 = mt * 16;

    // build A-frags (f32 -> bf16) and write zf
    bf16x8 A[9];
    const float* zr = z + (size_t)(m0 + fr) * IN_SZ + fg * 8;
    #pragma unroll
    for (int kt = 0; kt < NKT; ++kt) {
        float4 v0 = *(const float4*)(zr + kt * 32);
        float4 v1 = *(const float4*)(zr + kt * 32 + 4);
        bf16x8 a;
        a[0] = (short)f2bf(v0.x); a[1] = (short)f2bf(v0.y);
        a[2] = (short)f2bf(v0.z); a[3] = (short)f2bf(v0.w);
        a[4] = (short)f2bf(v1.x); a[5] = (short)f2bf(v1.y);
        a[6] = (short)f2bf(v1.z); a[7] = (short)f2bf(v1.w);
        A[kt] = a;
        *(bf16x8*)(zf + ((size_t)(mt * NKT + kt)) * 512 + l * 8) = a;
    }

    // gate layer 0: weight frags gathered from global (L2-resident, independent loads)
    #pragma unroll
    for (int nt = 0; nt < 4; ++nt) {
        f32x4 g = {0.f, 0.f, 0.f, 0.f};
        #pragma unroll
        for (int kt = 0; kt < NKT; ++kt) {
            float vals[8];
            #pragma unroll
            for (int j = 0; j < 8; ++j)
                vals[j] = g0_w[(kt * 32 + fg * 8 + j) * GH + nt * 16 + fr];
            bf16x8 b;
            #pragma unroll
            for (int j = 0; j < 8; ++j) b[j] = (short)f2bf(vals[j]);
            g = __builtin_amdgcn_mfma_f32_16x16x32_bf16(A[kt], b, g, 0, 0, 0);
        }
        float bias = g0_b[nt * 16 + fr];
        #pragma unroll
        for (int j = 0; j < 4; ++j)
            hscr[fg * 4 + j][nt * 16 + fr] = f2bf(elu_f(g[j] + bias));
    }
    __syncthreads();

    // gate layer 1
    {
        bf16x8 hA[2];
        #pragma unroll
        for (int kk = 0; kk < 2; ++kk)
            hA[kk] = *(const bf16x8*)&hscr[fr][kk * 32 + fg * 8];
        f32x4 gacc[4];
        #pragma unroll
        for (int nt = 0; nt < 4; ++nt) {
            f32x4 g = {0.f, 0.f, 0.f, 0.f};
            #pragma unroll
            for (int kk = 0; kk < 2; ++kk) {
                float vals[8];
                #pragma unroll
                for (int j = 0; j < 8; ++j)
                    vals[j] = g1_w[(kk * 32 + fg * 8 + j) * GH + nt * 16 + fr];
                bf16x8 b;
                #pragma unroll
                for (int j = 0; j < 8; ++j) b[j] = (short)f2bf(vals[j]);
                g = __builtin_amdgcn_mfma_f32_16x16x32_bf16(hA[kk], b, g, 0, 0, 0);
            }
            gacc[nt] = g;
        }
        __syncthreads();   // hA reads done before overwrite
        #pragma unroll
        for (int nt = 0; nt < 4; ++nt) {
            float bias = g1_b[nt * 16 + fr];
            #pragma unroll
            for (int j = 0; j < 4; ++j)
                hscr[fg * 4 + j][nt * 16 + fr] = f2bf(elu_f(gacc[nt][j] + bias));
        }
    }
    __syncthreads();

    // gate layer 2 -> logits
    {
        bf16x8 hA[2];
        #pragma unroll
        for (int kk = 0; kk < 2; ++kk)
            hA[kk] = *(const bf16x8*)&hscr[fr][kk * 32 + fg * 8];
        f32x4 g = {0.f, 0.f, 0.f, 0.f};
        #pragma unroll
        for (int kk = 0; kk < 2; ++kk) {
            float vals[8];
            #pragma unroll
            for (int j = 0; j < 8; ++j)
                vals[j] = (fr < E_NUM) ? g2_w[(kk * 32 + fg * 8 + j) * E_NUM + fr] : 0.0f;
            bf16x8 b;
            #pragma unroll
            for (int j = 0; j < 8; ++j) b[j] = (short)f2bf(vals[j]);
            g = __builtin_amdgcn_mfma_f32_16x16x32_bf16(hA[kk], b, g, 0, 0, 0);
        }
        if (fr < E_NUM) {
            float bias = g2_b[fr];
            #pragma unroll
            for (int j = 0; j < 4; ++j)
                lgs[fg * 4 + j][fr] = g[j] + bias;
        }
    }
    __syncthreads();

    // softmax per row (lanes 0..15 of each wave) -> coefT[e][b]
    if (l < 16) {
        float m = lgs[l][0];
        #pragma unroll
        for (int k = 1; k < E_NUM; ++k) m = fmaxf(m, lgs[l][k]);
        float s = 0.f;
        float ex[E_NUM];
        #pragma unroll
        for (int k = 0; k < E_NUM; ++k) { ex[k] = expf(lgs[l][k] - m); s += ex[k]; }
        float inv = 1.0f / s;
        #pragma unroll
        for (int k = 0; k < E_NUM; ++k)
            coefT[(size_t)k * B_TOTAL + m0 + l] = ex[k] * inv;
    }
}

// ================= k2: single-wave 32x16 GEMM, all experts, frag loads =================
// grid (64, 16), 64 thr: 2 row-tiles share each B-fragment (halves B L2 traffic).
__global__ __launch_bounds__(64) void gemm_kernel(
    const ushort* __restrict__ zf, const ushort* __restrict__ w2f,
    const float* __restrict__ coefT, const float* __restrict__ b2,
    float* __restrict__ out)
{
    const int l = threadIdx.x, fr = l & 15, fg = l >> 4;
    const int mt0 = blockIdx.x * 2, m0 = mt0 * 16;
    const int nt = blockIdx.y, n0 = nt * 16;

    bf16x8 A0[9], A1[9];
    #pragma unroll
    for (int kt = 0; kt < NKT; ++kt) {
        A0[kt] = *(const bf16x8*)(zf + ((size_t)(mt0 * NKT + kt)) * 512 + l * 8);
        A1[kt] = *(const bf16x8*)(zf + ((size_t)((mt0 + 1) * NKT + kt)) * 512 + l * 8);
    }

    const ushort* Bp = w2f + (size_t)nt * NKT * 512 + l * 8;

    f32x4 acc0 = {0.f, 0.f, 0.f, 0.f};
    f32x4 acc1 = {0.f, 0.f, 0.f, 0.f};
    bf16x8 B[9];
    #pragma unroll
    for (int kt = 0; kt < NKT; ++kt)
        B[kt] = *(const bf16x8*)(Bp + (size_t)kt * 512);

    #pragma unroll
    for (int e = 0; e < E_NUM; ++e) {
        bf16x8 Bn[9];
        if (e < E_NUM - 1) {
            #pragma unroll
            for (int kt = 0; kt < NKT; ++kt)
                Bn[kt] = *(const bf16x8*)(Bp + ((size_t)((e + 1) * 16 * NKT) + kt) * 512);
        }
        // 4 accumulator chains for MFMA ILP
        f32x4 p00 = {0.f, 0.f, 0.f, 0.f}, p01 = {0.f, 0.f, 0.f, 0.f};
        f32x4 p10 = {0.f, 0.f, 0.f, 0.f}, p11 = {0.f, 0.f, 0.f, 0.f};
        #pragma unroll
        for (int kt = 0; kt < 4; ++kt) {
            p00 = __builtin_amdgcn_mfma_f32_16x16x32_bf16(A0[kt], B[kt], p00, 0, 0, 0);
            p10 = __builtin_amdgcn_mfma_f32_16x16x32_bf16(A1[kt], B[kt], p10, 0, 0, 0);
            p01 = __builtin_amdgcn_mfma_f32_16x16x32_bf16(A0[kt + 4], B[kt + 4], p01, 0, 0, 0);
            p11 = __builtin_amdgcn_mfma_f32_16x16x32_bf16(A1[kt + 4], B[kt + 4], p11, 0, 0, 0);
        }
        p00 = __builtin_amdgcn_mfma_f32_16x16x32_bf16(A0[8], B[8], p00, 0, 0, 0);
        p10 = __builtin_amdgcn_mfma_f32_16x16x32_bf16(A1[8], B[8], p10, 0, 0, 0);

        float4 c0 = *(const float4*)(coefT + (size_t)e * B_TOTAL + m0 + fg * 4);
        float4 c1 = *(const float4*)(coefT + (size_t)e * B_TOTAL + m0 + 16 + fg * 4);
        float bv  = b2[e * OUT_N + n0 + fr];
        float c0a[4] = {c0.x, c0.y, c0.z, c0.w};
        float c1a[4] = {c1.x, c1.y, c1.z, c1.w};
        #pragma unroll
        for (int j = 0; j < 4; ++j) {
            acc0[j] = fmaf(c0a[j], p00[j] + p01[j] + bv, acc0[j]);
            acc1[j] = fmaf(c1a[j], p10[j] + p11[j] + bv, acc1[j]);
        }
        #pragma unroll
        for (int kt = 0; kt < NKT; ++kt) B[kt] = Bn[kt];
    }

    #pragma unroll
    for (int j = 0; j < 4; ++j) {
        out[(size_t)(m0 + fg * 4 + j) * OUT_N + n0 + fr]      = acc0[j];
        out[(size_t)(m0 + 16 + fg * 4 + j) * OUT_N + n0 + fr] = acc1[j];
    }
}

// ================= fallback (ws too small): f32 gate + direct =================
__global__ __launch_bounds__(64) void gate_fb_kernel(
    const float* __restrict__ z,
    const float* __restrict__ g0_w, const float* __restrict__ g0_b,
    const float* __restrict__ g1_w, const float* __restrict__ g1_b,
    const float* __restrict__ g2_w, const float* __restrict__ g2_b,
    float* __restrict__ coef)
{
    __shared__ float z_s[IN_SZ];
    __shared__ float h0_s[GH];
    __shared__ float h1_s[GH];
    const int b = blockIdx.x;
    const int t = threadIdx.x;
    const float* zr = z + (size_t)b * IN_SZ;
    for (int i = t; i < IN_SZ; i += 64) z_s[i] = zr[i];
    __syncthreads();
    float a0 = g0_b[t];
    for (int i = 0; i < IN_SZ; ++i) a0 = fmaf(z_s[i], g0_w[i * GH + t], a0);
    h0_s[t] = elu_f(a0);
    __syncthreads();
    float a1 = g1_b[t];
    for (int k = 0; k < GH; ++k) a1 = fmaf(h0_s[k], g1_w[k * GH + t], a1);
    h1_s[t] = elu_f(a1);
    __syncthreads();
    if (t < E_NUM) {
        float lg = g2_b[t];
        for (int k = 0; k < GH; ++k) lg = fmaf(h1_s[k], g2_w[k * E_NUM + t], lg);
        float m = lg;
        for (int d = 1; d < 8; d <<= 1) m = fmaxf(m, __shfl_xor(m, d, 8));
        float ex = expf(lg - m);
        float s = ex;
        for (int d = 1; d < 8; d <<= 1) s += __shfl_xor(s, d, 8);
        coef[b * E_NUM + t] = ex / s;
    }
}

__global__ __launch_bounds__(256) void direct_kernel(
    const float* __restrict__ z, const float* __restrict__ w2,
    const float* __restrict__ b2, const float* __restrict__ coef,
    float* __restrict__ out)
{
    __shared__ float z_s[8][IN_SZ];
    __shared__ float c_s[8][E_NUM];
    const int b0 = blockIdx.x * 8;
    const int t  = threadIdx.x;
    for (int idx = t; idx < 8 * IN_SZ; idx += 256)
        ((float*)z_s)[idx] = z[(size_t)b0 * IN_SZ + idx];
    if (t < 64) c_s[t >> 3][t & 7] = coef[b0 * E_NUM + t];
    __syncthreads();
    float outv[8];
    #pragma unroll
    for (int r = 0; r < 8; ++r) outv[r] = 0.0f;
    for (int e = 0; e < E_NUM; ++e) {
        const float* w = w2 + (size_t)e * IN_SZ * OUT_N + t;
        float tmp[8];
        #pragma unroll
        for (int r = 0; r < 8; ++r) tmp[r] = 0.0f;
        #pragma unroll 4
        for (int i = 0; i < IN_SZ; ++i) {
            float wv = w[i * OUT_N];
            #pragma unroll
            for (int r = 0; r < 8; ++r) tmp[r] += z_s[r][i] * wv;
        }
        float bv = b2[e * OUT_N + t];
        #pragma unroll
        for (int r = 0; r < 8; ++r) outv[r] += c_s[r][e] * (tmp[r] + bv);
    }
    #pragma unroll
    for (int r = 0; r < 8; ++r) out[(size_t)(b0 + r) * OUT_N + t] = outv[r];
}

extern "C" void kernel_launch(void* const* d_in, const int* in_sizes, int n_in,
                              void* d_out, int out_size, void* d_ws, size_t ws_size,
                              hipStream_t stream) {
    const float* z    = (const float*)d_in[0];
    const float* g0_w = (const float*)d_in[1];
    const float* g0_b = (const float*)d_in[2];
    const float* g1_w = (const float*)d_in[3];
    const float* g1_b = (const float*)d_in[4];
    const float* g2_w = (const float*)d_in[5];
    const float* g2_b = (const float*)d_in[6];
    // d_in[7..10] = w0,b0,w1,b1 are dead in the reference (layer_out never fed back)
    const float* w2   = (const float*)d_in[11];
    const float* b2   = (const float*)d_in[12];
    float* out = (float*)d_out;

    const size_t w2f_b   = (size_t)E_NUM * 16 * NKT * 1024;          // 1.18 MB
    const size_t zf_b    = (size_t)128 * NKT * 1024;                 // 1.18 MB
    const size_t coefT_b = (size_t)E_NUM * B_TOTAL * sizeof(float);  // 64 KB

    char* p = (char*)d_ws;
    ushort* w2f   = (ushort*)p;            p += w2f_b;
    ushort* zf    = (ushort*)p;            p += zf_b;
    float*  coefT = (float*)p;

    if (ws_size >= w2f_b + zf_b + coefT_b) {
        prep_kernel<<<W2F_BLKS + ZG_BLKS, 256, 0, stream>>>(
            w2, z, g0_w, g0_b, g1_w, g1_b, g2_w, g2_b, w2f, zf, coefT);
        gemm_kernel<<<dim3(B_TOTAL / 32, OUT_N / 16), 64, 0, stream>>>(
            zf, w2f, coefT, b2, out);
    } else {
        float* coef = (float*)d_ws;
        gate_fb_kernel<<<B_TOTAL, 64, 0, stream>>>(z, g0_w, g0_b, g1_w, g1_b,
                                                   g2_w, g2_b, coef);
        direct_kernel<<<B_TOTAL / 8, 256, 0, stream>>>(z, w2, b2, coef, out);
    }
}

// Round 10
// 25.610 us; speedup vs baseline: 1.2307x; 1.2307x over previous
//
#include <hip/hip_runtime.h>
#include <hip/hip_bf16.h>

#define B_TOTAL 2048
#define IN_SZ   288
#define GH      64
#define E_NUM   8
#define OUT_N   256
#define NKT     9                 // k-tiles of 32 per expert

#define W2F_BLKS 72               // one (e,kt) slab each
#define ZF_BLKS  32               // 64 rows each
#define GWF_FRAGS 46              // 36 g0 + 8 g1 + 2 g2

typedef __attribute__((ext_vector_type(8))) short bf16x8;
typedef __attribute__((ext_vector_type(4))) float f32x4;

__device__ __forceinline__ float elu_f(float x) {
    return x > 0.0f ? x : (expf(x) - 1.0f);
}
__device__ __forceinline__ ushort f2bf(float f) {
    __hip_bfloat16 h = __float2bfloat16(f);
    return *reinterpret_cast<ushort*>(&h);
}

// ================= k1: build ALL fragment-major operands (r8-validated, verbatim) =================
// blocks [0,72):      w2 -> w2f frag (e,nt,kt): lane l 16B = cols nt*16+(l&15), k kt*32+(l>>4)*8..+7
// blocks [72,104):    z  -> zf  frag (mt,kt):   lane l 16B = row mt*16+(l&15), same k pattern
// block  104:         gate weights -> gwf frags (same lane pattern; g2 cols 8..15 zero)
__global__ __launch_bounds__(256) void prep_kernel(
    const float* __restrict__ w2, const float* __restrict__ z,
    const float* __restrict__ g0_w, const float* __restrict__ g1_w,
    const float* __restrict__ g2_w,
    ushort* __restrict__ w2f, ushort* __restrict__ zf, ushort* __restrict__ gwf)
{
    __shared__ float ts[32][260];
    const int t = threadIdx.x;
    const int wid = t >> 6, l = t & 63;
    const int fr = l & 15, fg = l >> 4;

    if (blockIdx.x < W2F_BLKS) {
        const int e  = blockIdx.x / NKT;
        const int kt = blockIdx.x - e * NKT;
        const float* src = w2 + ((size_t)e * IN_SZ + kt * 32) * OUT_N;
        #pragma unroll
        for (int q = t; q < 2048; q += 256) {            // 32 rows x 64 float4
            int r = q >> 6, c4 = q & 63;
            *(float4*)&ts[r][c4 * 4] = *(const float4*)(src + (size_t)r * OUT_N + c4 * 4);
        }
        __syncthreads();
        #pragma unroll
        for (int it = 0; it < 4; ++it) {
            int q = t + it * 256;
            int nt = q >> 6, ll = q & 63;
            int qfr = ll & 15, qfg = ll >> 4;
            ushort4 u0, u1;
            u0.x = f2bf(ts[qfg * 8 + 0][nt * 16 + qfr]);
            u0.y = f2bf(ts[qfg * 8 + 1][nt * 16 + qfr]);
            u0.z = f2bf(ts[qfg * 8 + 2][nt * 16 + qfr]);
            u0.w = f2bf(ts[qfg * 8 + 3][nt * 16 + qfr]);
            u1.x = f2bf(ts[qfg * 8 + 4][nt * 16 + qfr]);
            u1.y = f2bf(ts[qfg * 8 + 5][nt * 16 + qfr]);
            u1.z = f2bf(ts[qfg * 8 + 6][nt * 16 + qfr]);
            u1.w = f2bf(ts[qfg * 8 + 7][nt * 16 + qfr]);
            size_t off = ((size_t)((e * 16 + nt) * NKT + kt)) * 512 + ll * 8;
            *(ushort4*)&w2f[off]     = u0;
            *(ushort4*)&w2f[off + 4] = u1;
        }
        return;
    }

    if (blockIdx.x < W2F_BLKS + ZF_BLKS) {
        const int mt = (blockIdx.x - W2F_BLKS) * 4 + wid;   // 0..127
        const int m0 = mt * 16;
        const float* zr = z + (size_t)(m0 + fr) * IN_SZ + fg * 8;
        #pragma unroll
        for (int kt = 0; kt < NKT; ++kt) {
            float4 v0 = *(const float4*)(zr + kt * 32);
            float4 v1 = *(const float4*)(zr + kt * 32 + 4);
            ushort4 u0, u1;
            u0.x = f2bf(v0.x); u0.y = f2bf(v0.y); u0.z = f2bf(v0.z); u0.w = f2bf(v0.w);
            u1.x = f2bf(v1.x); u1.y = f2bf(v1.y); u1.z = f2bf(v1.z); u1.w = f2bf(v1.w);
            size_t off = ((size_t)(mt * NKT + kt)) * 512 + l * 8;
            *(ushort4*)&zf[off]     = u0;
            *(ushort4*)&zf[off + 4] = u1;
        }
        return;
    }

    // gate-weight fragments
    for (int fid = wid; fid < GWF_FRAGS; fid += 4) {
        float vals[8];
        if (fid < 36) {
            int nt = fid / NKT, kt = fid - nt * NKT;
            #pragma unroll
            for (int j = 0; j < 8; ++j) {
                int k = kt * 32 + fg * 8 + j;
                vals[j] = g0_w[k * GH + nt * 16 + fr];
            }
        } else if (fid < 44) {
            int q = fid - 36, nt = q >> 1, kk = q & 1;
            #pragma unroll
            for (int j = 0; j < 8; ++j) {
                int k = kk * 32 + fg * 8 + j;
                vals[j] = g1_w[k * GH + nt * 16 + fr];
            }
        } else {
            int kk = fid - 44;
            #pragma unroll
            for (int j = 0; j < 8; ++j) {
                int k = kk * 32 + fg * 8 + j;
                vals[j] = (fr < E_NUM) ? g2_w[k * E_NUM + fr] : 0.0f;
            }
        }
        ushort4 u0, u1;
        u0.x = f2bf(vals[0]); u0.y = f2bf(vals[1]); u0.z = f2bf(vals[2]); u0.w = f2bf(vals[3]);
        u1.x = f2bf(vals[4]); u1.y = f2bf(vals[5]); u1.z = f2bf(vals[6]); u1.w = f2bf(vals[7]);
        size_t off = (size_t)fid * 512 + l * 8;
        *(ushort4*)&gwf[off]     = u0;
        *(ushort4*)&gwf[off + 4] = u1;
    }
}

// ================= k2: gate MLP from fragments -> coefT (r8 logic, 1 wave/block, 128 blocks) =================
__global__ __launch_bounds__(64) void gate_kernel(
    const ushort* __restrict__ zf, const ushort* __restrict__ gwf,
    const float* __restrict__ g0_b, const float* __restrict__ g1_b,
    const float* __restrict__ g2_b,
    float* __restrict__ coefT)
{
    __shared__ ushort hscr[16][72];
    __shared__ float  lgs[16][8];

    const int l = threadIdx.x;
    const int fr = l & 15, fg = l >> 4, fk = fg * 8;
    const int mt = blockIdx.x;            // 0..127
    const int m0 = mt * 16;

    bf16x8 A[9];
    #pragma unroll
    for (int kt = 0; kt < NKT; ++kt)
        A[kt] = *(const bf16x8*)(zf + ((size_t)(mt * NKT + kt)) * 512 + l * 8);

    // layer 0
    #pragma unroll
    for (int nt = 0; nt < 4; ++nt) {
        f32x4 g = {0.f, 0.f, 0.f, 0.f};
        #pragma unroll
        for (int kt = 0; kt < NKT; ++kt) {
            bf16x8 b = *(const bf16x8*)(gwf + ((size_t)(nt * NKT + kt)) * 512 + l * 8);
            g = __builtin_amdgcn_mfma_f32_16x16x32_bf16(A[kt], b, g, 0, 0, 0);
        }
        float bias = g0_b[nt * 16 + fr];
        #pragma unroll
        for (int j = 0; j < 4; ++j)
            hscr[fg * 4 + j][nt * 16 + fr] = f2bf(elu_f(g[j] + bias));
    }
    __syncthreads();

    // layer 1
    {
        bf16x8 hA[2];
        #pragma unroll
        for (int kk = 0; kk < 2; ++kk)
            hA[kk] = *(const bf16x8*)&hscr[fr][kk * 32 + fk];
        f32x4 gacc[4];
        #pragma unroll
        for (int nt = 0; nt < 4; ++nt) {
            f32x4 g = {0.f, 0.f, 0.f, 0.f};
            #pragma unroll
            for (int kk = 0; kk < 2; ++kk) {
                bf16x8 b = *(const bf16x8*)(gwf + ((size_t)(36 + nt * 2 + kk)) * 512 + l * 8);
                g = __builtin_amdgcn_mfma_f32_16x16x32_bf16(hA[kk], b, g, 0, 0, 0);
            }
            gacc[nt] = g;
        }
        __syncthreads();
        #pragma unroll
        for (int nt = 0; nt < 4; ++nt) {
            float bias = g1_b[nt * 16 + fr];
            #pragma unroll
            for (int j = 0; j < 4; ++j)
                hscr[fg * 4 + j][nt * 16 + fr] = f2bf(elu_f(gacc[nt][j] + bias));
        }
    }
    __syncthreads();

    // layer 2 -> logits
    {
        bf16x8 hA[2];
        #pragma unroll
        for (int kk = 0; kk < 2; ++kk)
            hA[kk] = *(const bf16x8*)&hscr[fr][kk * 32 + fk];
        f32x4 g = {0.f, 0.f, 0.f, 0.f};
        #pragma unroll
        for (int kk = 0; kk < 2; ++kk) {
            bf16x8 b = *(const bf16x8*)(gwf + ((size_t)(44 + kk)) * 512 + l * 8);
            g = __builtin_amdgcn_mfma_f32_16x16x32_bf16(hA[kk], b, g, 0, 0, 0);
        }
        if (fr < E_NUM) {
            float bias = g2_b[fr];
            #pragma unroll
            for (int j = 0; j < 4; ++j)
                lgs[fg * 4 + j][fr] = g[j] + bias;
        }
    }
    __syncthreads();

    // softmax -> coefT[e][b]
    if (l < 16) {
        float m = lgs[l][0];
        #pragma unroll
        for (int k = 1; k < E_NUM; ++k) m = fmaxf(m, lgs[l][k]);
        float s = 0.f;
        float ex[E_NUM];
        #pragma unroll
        for (int k = 0; k < E_NUM; ++k) { ex[k] = expf(lgs[l][k] - m); s += ex[k]; }
        float inv = 1.0f / s;
        #pragma unroll
        for (int k = 0; k < E_NUM; ++k)
            coefT[(size_t)k * B_TOTAL + m0 + l] = ex[k] * inv;
    }
}

// ================= k3: 2-wave expert-split 16x16 GEMM =================
// grid (128, 16), 128 thr. Wave w handles experts [4w, 4w+4); LDS combine.
__global__ __launch_bounds__(128) void gemm_kernel(
    const ushort* __restrict__ zf, const ushort* __restrict__ w2f,
    const float* __restrict__ coefT, const float* __restrict__ b2,
    float* __restrict__ out)
{
    __shared__ float xfer[64][4];
    const int t = threadIdx.x, wv = t >> 6, l = t & 63;
    const int fr = l & 15, fg = l >> 4;
    const int mt = blockIdx.x, m0 = mt * 16;
    const int nt = blockIdx.y, n0 = nt * 16;

    bf16x8 A[9];
    #pragma unroll
    for (int kt = 0; kt < NKT; ++kt)
        A[kt] = *(const bf16x8*)(zf + ((size_t)(mt * NKT + kt)) * 512 + l * 8);

    const ushort* Bp = w2f + (size_t)nt * NKT * 512 + l * 8;
    const int e0 = wv * 4;

    f32x4 acc = {0.f, 0.f, 0.f, 0.f};
    bf16x8 B[9];
    #pragma unroll
    for (int kt = 0; kt < NKT; ++kt)
        B[kt] = *(const bf16x8*)(Bp + ((size_t)(e0 * 16 * NKT) + kt) * 512);

    #pragma unroll
    for (int ee = 0; ee < 4; ++ee) {
        const int e = e0 + ee;
        bf16x8 Bn[9];
        if (ee < 3) {
            #pragma unroll
            for (int kt = 0; kt < NKT; ++kt)
                Bn[kt] = *(const bf16x8*)(Bp + ((size_t)((e + 1) * 16 * NKT) + kt) * 512);
        }
        // two interleaved accumulator chains
        f32x4 p0 = {0.f, 0.f, 0.f, 0.f};
        f32x4 p1 = {0.f, 0.f, 0.f, 0.f};
        p0 = __builtin_amdgcn_mfma_f32_16x16x32_bf16(A[0], B[0], p0, 0, 0, 0);
        p1 = __builtin_amdgcn_mfma_f32_16x16x32_bf16(A[1], B[1], p1, 0, 0, 0);
        p0 = __builtin_amdgcn_mfma_f32_16x16x32_bf16(A[2], B[2], p0, 0, 0, 0);
        p1 = __builtin_amdgcn_mfma_f32_16x16x32_bf16(A[3], B[3], p1, 0, 0, 0);
        p0 = __builtin_amdgcn_mfma_f32_16x16x32_bf16(A[4], B[4], p0, 0, 0, 0);
        p1 = __builtin_amdgcn_mfma_f32_16x16x32_bf16(A[5], B[5], p1, 0, 0, 0);
        p0 = __builtin_amdgcn_mfma_f32_16x16x32_bf16(A[6], B[6], p0, 0, 0, 0);
        p1 = __builtin_amdgcn_mfma_f32_16x16x32_bf16(A[7], B[7], p1, 0, 0, 0);
        p0 = __builtin_amdgcn_mfma_f32_16x16x32_bf16(A[8], B[8], p0, 0, 0, 0);

        float4 cv = *(const float4*)(coefT + (size_t)e * B_TOTAL + m0 + fg * 4);
        float bv  = b2[e * OUT_N + n0 + fr];
        float ca[4] = {cv.x, cv.y, cv.z, cv.w};
        #pragma unroll
        for (int j = 0; j < 4; ++j)
            acc[j] = fmaf(ca[j], p0[j] + p1[j] + bv, acc[j]);

        #pragma unroll
        for (int kt = 0; kt < NKT; ++kt) B[kt] = Bn[kt];
    }

    if (wv == 1) {
        #pragma unroll
        for (int j = 0; j < 4; ++j) xfer[l][j] = acc[j];
    }
    __syncthreads();
    if (wv == 0) {
        #pragma unroll
        for (int j = 0; j < 4; ++j)
            out[(size_t)(m0 + fg * 4 + j) * OUT_N + n0 + fr] = acc[j] + xfer[l][j];
    }
}

// ================= fallback (ws too small): f32 gate + direct =================
__global__ __launch_bounds__(64) void gate_fb_kernel(
    const float* __restrict__ z,
    const float* __restrict__ g0_w, const float* __restrict__ g0_b,
    const float* __restrict__ g1_w, const float* __restrict__ g1_b,
    const float* __restrict__ g2_w, const float* __restrict__ g2_b,
    float* __restrict__ coef)
{
    __shared__ float z_s[IN_SZ];
    __shared__ float h0_s[GH];
    __shared__ float h1_s[GH];
    const int b = blockIdx.x;
    const int t = threadIdx.x;
    const float* zr = z + (size_t)b * IN_SZ;
    for (int i = t; i < IN_SZ; i += 64) z_s[i] = zr[i];
    __syncthreads();
    float a0 = g0_b[t];
    for (int i = 0; i < IN_SZ; ++i) a0 = fmaf(z_s[i], g0_w[i * GH + t], a0);
    h0_s[t] = elu_f(a0);
    __syncthreads();
    float a1 = g1_b[t];
    for (int k = 0; k < GH; ++k) a1 = fmaf(h0_s[k], g1_w[k * GH + t], a1);
    h1_s[t] = elu_f(a1);
    __syncthreads();
    if (t < E_NUM) {
        float lg = g2_b[t];
        for (int k = 0; k < GH; ++k) lg = fmaf(h1_s[k], g2_w[k * E_NUM + t], lg);
        float m = lg;
        for (int d = 1; d < 8; d <<= 1) m = fmaxf(m, __shfl_xor(m, d, 8));
        float ex = expf(lg - m);
        float s = ex;
        for (int d = 1; d < 8; d <<= 1) s += __shfl_xor(s, d, 8);
        coef[b * E_NUM + t] = ex / s;
    }
}

__global__ __launch_bounds__(256) void direct_kernel(
    const float* __restrict__ z, const float* __restrict__ w2,
    const float* __restrict__ b2, const float* __restrict__ coef,
    float* __restrict__ out)
{
    __shared__ float z_s[8][IN_SZ];
    __shared__ float c_s[8][E_NUM];
    const int b0 = blockIdx.x * 8;
    const int t  = threadIdx.x;
    for (int idx = t; idx < 8 * IN_SZ; idx += 256)
        ((float*)z_s)[idx] = z[(size_t)b0 * IN_SZ + idx];
    if (t < 64) c_s[t >> 3][t & 7] = coef[b0 * E_NUM + t];
    __syncthreads();
    float outv[8];
    #pragma unroll
    for (int r = 0; r < 8; ++r) outv[r] = 0.0f;
    for (int e = 0; e < E_NUM; ++e) {
        const float* w = w2 + (size_t)e * IN_SZ * OUT_N + t;
        float tmp[8];
        #pragma unroll
        for (int r = 0; r < 8; ++r) tmp[r] = 0.0f;
        #pragma unroll 4
        for (int i = 0; i < IN_SZ; ++i) {
            float wv = w[i * OUT_N];
            #pragma unroll
            for (int r = 0; r < 8; ++r) tmp[r] += z_s[r][i] * wv;
        }
        float bv = b2[e * OUT_N + t];
        #pragma unroll
        for (int r = 0; r < 8; ++r) outv[r] += c_s[r][e] * (tmp[r] + bv);
    }
    #pragma unroll
    for (int r = 0; r < 8; ++r) out[(size_t)(b0 + r) * OUT_N + t] = outv[r];
}

extern "C" void kernel_launch(void* const* d_in, const int* in_sizes, int n_in,
                              void* d_out, int out_size, void* d_ws, size_t ws_size,
                              hipStream_t stream) {
    const float* z    = (const float*)d_in[0];
    const float* g0_w = (const float*)d_in[1];
    const float* g0_b = (const float*)d_in[2];
    const float* g1_w = (const float*)d_in[3];
    const float* g1_b = (const float*)d_in[4];
    const float* g2_w = (const float*)d_in[5];
    const float* g2_b = (const float*)d_in[6];
    // d_in[7..10] = w0,b0,w1,b1 are dead in the reference (layer_out never fed back)
    const float* w2   = (const float*)d_in[11];
    const float* b2   = (const float*)d_in[12];
    float* out = (float*)d_out;

    const size_t w2f_b   = (size_t)E_NUM * 16 * NKT * 1024;          // 1.18 MB
    const size_t zf_b    = (size_t)128 * NKT * 1024;                 // 1.18 MB
    const size_t gwf_b   = (size_t)GWF_FRAGS * 1024;                 // 47 KB
    const size_t coefT_b = (size_t)E_NUM * B_TOTAL * sizeof(float);  // 64 KB

    char* p = (char*)d_ws;
    ushort* w2f   = (ushort*)p;            p += w2f_b;
    ushort* zf    = (ushort*)p;            p += zf_b;
    ushort* gwf   = (ushort*)p;            p += gwf_b;
    float*  coefT = (float*)p;

    if (ws_size >= w2f_b + zf_b + gwf_b + coefT_b) {
        prep_kernel<<<W2F_BLKS + ZF_BLKS + 1, 256, 0, stream>>>(
            w2, z, g0_w, g1_w, g2_w, w2f, zf, gwf);
        gate_kernel<<<128, 64, 0, stream>>>(zf, gwf, g0_b, g1_b, g2_b, coefT);
        gemm_kernel<<<dim3(B_TOTAL / 16, OUT_N / 16), 128, 0, stream>>>(
            zf, w2f, coefT, b2, out);
    } else {
        float* coef = (float*)d_ws;
        gate_fb_kernel<<<B_TOTAL, 64, 0, stream>>>(z, g0_w, g0_b, g1_w, g1_b,
                                                   g2_w, g2_b, coef);
        direct_kernel<<<B_TOTAL / 8, 256, 0, stream>>>(z, w2, b2, coef, out);
    }
}

// Round 11
// 22.633 us; speedup vs baseline: 1.3925x; 1.1315x over previous
//
#include <hip/hip_runtime.h>
#include <hip/hip_bf16.h>

#define B_TOTAL 2048
#define IN_SZ   288
#define GH      64
#define E_NUM   8
#define OUT_N   256
#define NKT     9                 // k-tiles of 32 per expert

#define W2F_BLKS 72               // one (e,kt) slab each
#define ZF_BLKS  32               // 64 rows each
#define GWF_BLKS 4
#define GWF_FRAGS 46              // 36 g0 + 8 g1 + 2 g2

typedef __attribute__((ext_vector_type(8))) short bf16x8;
typedef __attribute__((ext_vector_type(4))) float f32x4;

__device__ __forceinline__ float elu_f(float x) {
    return x > 0.0f ? x : (expf(x) - 1.0f);
}
__device__ __forceinline__ ushort f2bf(float f) {
    __hip_bfloat16 h = __float2bfloat16(f);
    return *reinterpret_cast<ushort*>(&h);
}

// ================= k1: build ALL fragment-major operands (r8-validated) =================
// blocks [0,72):    w2 -> w2f frag (e,nt,kt): lane l 16B = cols nt*16+(l&15), k kt*32+(l>>4)*8..+7
// blocks [72,104):  z  -> zf  frag (mt,kt):   lane l 16B = row mt*16+(l&15), same k pattern
// blocks [104,108): gate weights -> gwf frags (46 frags spread over 16 waves)
__global__ __launch_bounds__(256) void prep_kernel(
    const float* __restrict__ w2, const float* __restrict__ z,
    const float* __restrict__ g0_w, const float* __restrict__ g1_w,
    const float* __restrict__ g2_w,
    ushort* __restrict__ w2f, ushort* __restrict__ zf, ushort* __restrict__ gwf)
{
    __shared__ float ts[32][260];
    const int t = threadIdx.x;
    const int wid = t >> 6, l = t & 63;
    const int fr = l & 15, fg = l >> 4;

    if (blockIdx.x < W2F_BLKS) {
        const int e  = blockIdx.x / NKT;
        const int kt = blockIdx.x - e * NKT;
        const float* src = w2 + ((size_t)e * IN_SZ + kt * 32) * OUT_N;
        #pragma unroll
        for (int q = t; q < 2048; q += 256) {            // 32 rows x 64 float4
            int r = q >> 6, c4 = q & 63;
            *(float4*)&ts[r][c4 * 4] = *(const float4*)(src + (size_t)r * OUT_N + c4 * 4);
        }
        __syncthreads();
        #pragma unroll
        for (int it = 0; it < 4; ++it) {
            int q = t + it * 256;
            int nt = q >> 6, ll = q & 63;
            int qfr = ll & 15, qfg = ll >> 4;
            ushort4 u0, u1;
            u0.x = f2bf(ts[qfg * 8 + 0][nt * 16 + qfr]);
            u0.y = f2bf(ts[qfg * 8 + 1][nt * 16 + qfr]);
            u0.z = f2bf(ts[qfg * 8 + 2][nt * 16 + qfr]);
            u0.w = f2bf(ts[qfg * 8 + 3][nt * 16 + qfr]);
            u1.x = f2bf(ts[qfg * 8 + 4][nt * 16 + qfr]);
            u1.y = f2bf(ts[qfg * 8 + 5][nt * 16 + qfr]);
            u1.z = f2bf(ts[qfg * 8 + 6][nt * 16 + qfr]);
            u1.w = f2bf(ts[qfg * 8 + 7][nt * 16 + qfr]);
            size_t off = ((size_t)((e * 16 + nt) * NKT + kt)) * 512 + ll * 8;
            *(ushort4*)&w2f[off]     = u0;
            *(ushort4*)&w2f[off + 4] = u1;
        }
        return;
    }

    if (blockIdx.x < W2F_BLKS + ZF_BLKS) {
        const int mt = (blockIdx.x - W2F_BLKS) * 4 + wid;   // 0..127
        const int m0 = mt * 16;
        const float* zr = z + (size_t)(m0 + fr) * IN_SZ + fg * 8;
        #pragma unroll
        for (int kt = 0; kt < NKT; ++kt) {
            float4 v0 = *(const float4*)(zr + kt * 32);
            float4 v1 = *(const float4*)(zr + kt * 32 + 4);
            ushort4 u0, u1;
            u0.x = f2bf(v0.x); u0.y = f2bf(v0.y); u0.z = f2bf(v0.z); u0.w = f2bf(v0.w);
            u1.x = f2bf(v1.x); u1.y = f2bf(v1.y); u1.z = f2bf(v1.z); u1.w = f2bf(v1.w);
            size_t off = ((size_t)(mt * NKT + kt)) * 512 + l * 8;
            *(ushort4*)&zf[off]     = u0;
            *(ushort4*)&zf[off + 4] = u1;
        }
        return;
    }

    // gate-weight fragments (46 frags over 4 blocks x 4 waves)
    const int base = (blockIdx.x - W2F_BLKS - ZF_BLKS) * 4 + wid;
    for (int fid = base; fid < GWF_FRAGS; fid += 16) {
        float vals[8];
        if (fid < 36) {
            int nt = fid / NKT, kt = fid - nt * NKT;
            #pragma unroll
            for (int j = 0; j < 8; ++j) {
                int k = kt * 32 + fg * 8 + j;
                vals[j] = g0_w[k * GH + nt * 16 + fr];
            }
        } else if (fid < 44) {
            int q = fid - 36, nt = q >> 1, kk = q & 1;
            #pragma unroll
            for (int j = 0; j < 8; ++j) {
                int k = kk * 32 + fg * 8 + j;
                vals[j] = g1_w[k * GH + nt * 16 + fr];
            }
        } else {
            int kk = fid - 44;
            #pragma unroll
            for (int j = 0; j < 8; ++j) {
                int k = kk * 32 + fg * 8 + j;
                vals[j] = (fr < E_NUM) ? g2_w[k * E_NUM + fr] : 0.0f;
            }
        }
        ushort4 u0, u1;
        u0.x = f2bf(vals[0]); u0.y = f2bf(vals[1]); u0.z = f2bf(vals[2]); u0.w = f2bf(vals[3]);
        u1.x = f2bf(vals[4]); u1.y = f2bf(vals[5]); u1.z = f2bf(vals[6]); u1.w = f2bf(vals[7]);
        size_t off = (size_t)fid * 512 + l * 8;
        *(ushort4*)&gwf[off]     = u0;
        *(ushort4*)&gwf[off + 4] = u1;
    }
}

// ================= k2: fused gate + GEMM =================
// grid (64, 16), 128 thr = 2 waves. Wave wv owns mt = bx*2+wv (16 rows x 16 cols).
// Gate recomputed per wave (13 MFMAs, gwf frags L1-shared); coef stays in LDS.
// Both waves share the same nt B-fragments via L1 -> B L2 traffic halves vs r8.
__global__ __launch_bounds__(128) void fused_kernel(
    const ushort* __restrict__ zf, const ushort* __restrict__ w2f,
    const ushort* __restrict__ gwf,
    const float* __restrict__ g0_b, const float* __restrict__ g1_b,
    const float* __restrict__ g2_b, const float* __restrict__ b2,
    float* __restrict__ out)
{
    __shared__ ushort hscr[2][16][72];
    __shared__ float  lgs[2][16][8];
    __shared__ float  cfsT[2][E_NUM][16];

    const int t = threadIdx.x, wv = t >> 6, l = t & 63;
    const int fr = l & 15, fg = l >> 4, fk = fg * 8;
    const int mt = blockIdx.x * 2 + wv, m0 = mt * 16;
    const int nt = blockIdx.y, n0 = nt * 16;

    // A fragments (shared by gate layer0 and the main GEMM)
    bf16x8 A[9];
    #pragma unroll
    for (int kt = 0; kt < NKT; ++kt)
        A[kt] = *(const bf16x8*)(zf + ((size_t)(mt * NKT + kt)) * 512 + l * 8);

    // ---- gate layer 0 (r8-validated mapping) ----
    #pragma unroll
    for (int ng = 0; ng < 4; ++ng) {
        f32x4 g = {0.f, 0.f, 0.f, 0.f};
        #pragma unroll
        for (int kt = 0; kt < NKT; ++kt) {
            bf16x8 b = *(const bf16x8*)(gwf + ((size_t)(ng * NKT + kt)) * 512 + l * 8);
            g = __builtin_amdgcn_mfma_f32_16x16x32_bf16(A[kt], b, g, 0, 0, 0);
        }
        float bias = g0_b[ng * 16 + fr];
        #pragma unroll
        for (int j = 0; j < 4; ++j)
            hscr[wv][fg * 4 + j][ng * 16 + fr] = f2bf(elu_f(g[j] + bias));
    }
    __syncthreads();

    // ---- gate layer 1 ----
    {
        bf16x8 hA[2];
        #pragma unroll
        for (int kk = 0; kk < 2; ++kk)
            hA[kk] = *(const bf16x8*)&hscr[wv][fr][kk * 32 + fk];
        f32x4 gacc[4];
        #pragma unroll
        for (int ng = 0; ng < 4; ++ng) {
            f32x4 g = {0.f, 0.f, 0.f, 0.f};
            #pragma unroll
            for (int kk = 0; kk < 2; ++kk) {
                bf16x8 b = *(const bf16x8*)(gwf + ((size_t)(36 + ng * 2 + kk)) * 512 + l * 8);
                g = __builtin_amdgcn_mfma_f32_16x16x32_bf16(hA[kk], b, g, 0, 0, 0);
            }
            gacc[ng] = g;
        }
        __syncthreads();
        #pragma unroll
        for (int ng = 0; ng < 4; ++ng) {
            float bias = g1_b[ng * 16 + fr];
            #pragma unroll
            for (int j = 0; j < 4; ++j)
                hscr[wv][fg * 4 + j][ng * 16 + fr] = f2bf(elu_f(gacc[ng][j] + bias));
        }
    }
    __syncthreads();

    // ---- gate layer 2 -> logits ----
    {
        bf16x8 hA[2];
        #pragma unroll
        for (int kk = 0; kk < 2; ++kk)
            hA[kk] = *(const bf16x8*)&hscr[wv][fr][kk * 32 + fk];
        f32x4 g = {0.f, 0.f, 0.f, 0.f};
        #pragma unroll
        for (int kk = 0; kk < 2; ++kk) {
            bf16x8 b = *(const bf16x8*)(gwf + ((size_t)(44 + kk)) * 512 + l * 8);
            g = __builtin_amdgcn_mfma_f32_16x16x32_bf16(hA[kk], b, g, 0, 0, 0);
        }
        if (fr < E_NUM) {
            float bias = g2_b[fr];
            #pragma unroll
            for (int j = 0; j < 4; ++j)
                lgs[wv][fg * 4 + j][fr] = g[j] + bias;
        }
    }
    __syncthreads();

    // ---- softmax per row (lanes 0..15 of each wave) -> cfsT[wv][e][row] ----
    if (l < 16) {
        float m = lgs[wv][l][0];
        #pragma unroll
        for (int k = 1; k < E_NUM; ++k) m = fmaxf(m, lgs[wv][l][k]);
        float s = 0.f;
        float ex[E_NUM];
        #pragma unroll
        for (int k = 0; k < E_NUM; ++k) { ex[k] = expf(lgs[wv][l][k] - m); s += ex[k]; }
        float inv = 1.0f / s;
        #pragma unroll
        for (int k = 0; k < E_NUM; ++k) cfsT[wv][k][l] = ex[k] * inv;
    }
    __syncthreads();

    // ---- main GEMM: per-expert partials, scaled accumulate (r8-validated) ----
    const ushort* Bp = w2f + (size_t)nt * NKT * 512 + l * 8;

    f32x4 acc = {0.f, 0.f, 0.f, 0.f};
    bf16x8 B[9];
    #pragma unroll
    for (int kt = 0; kt < NKT; ++kt)
        B[kt] = *(const bf16x8*)(Bp + (size_t)kt * 512);

    #pragma unroll
    for (int e = 0; e < E_NUM; ++e) {
        bf16x8 Bn[9];
        if (e < E_NUM - 1) {
            #pragma unroll
            for (int kt = 0; kt < NKT; ++kt)
                Bn[kt] = *(const bf16x8*)(Bp + ((size_t)((e + 1) * 16 * NKT) + kt) * 512);
        }
        f32x4 p0 = {0.f, 0.f, 0.f, 0.f};
        f32x4 p1 = {0.f, 0.f, 0.f, 0.f};
        p0 = __builtin_amdgcn_mfma_f32_16x16x32_bf16(A[0], B[0], p0, 0, 0, 0);
        p1 = __builtin_amdgcn_mfma_f32_16x16x32_bf16(A[1], B[1], p1, 0, 0, 0);
        p0 = __builtin_amdgcn_mfma_f32_16x16x32_bf16(A[2], B[2], p0, 0, 0, 0);
        p1 = __builtin_amdgcn_mfma_f32_16x16x32_bf16(A[3], B[3], p1, 0, 0, 0);
        p0 = __builtin_amdgcn_mfma_f32_16x16x32_bf16(A[4], B[4], p0, 0, 0, 0);
        p1 = __builtin_amdgcn_mfma_f32_16x16x32_bf16(A[5], B[5], p1, 0, 0, 0);
        p0 = __builtin_amdgcn_mfma_f32_16x16x32_bf16(A[6], B[6], p0, 0, 0, 0);
        p1 = __builtin_amdgcn_mfma_f32_16x16x32_bf16(A[7], B[7], p1, 0, 0, 0);
        p0 = __builtin_amdgcn_mfma_f32_16x16x32_bf16(A[8], B[8], p0, 0, 0, 0);

        float4 cv = *(const float4*)&cfsT[wv][e][fg * 4];
        float bv  = b2[e * OUT_N + n0 + fr];
        float ca[4] = {cv.x, cv.y, cv.z, cv.w};
        #pragma unroll
        for (int j = 0; j < 4; ++j)
            acc[j] = fmaf(ca[j], p0[j] + p1[j] + bv, acc[j]);

        #pragma unroll
        for (int kt = 0; kt < NKT; ++kt) B[kt] = Bn[kt];
    }

    #pragma unroll
    for (int j = 0; j < 4; ++j)
        out[(size_t)(m0 + fg * 4 + j) * OUT_N + n0 + fr] = acc[j];
}

// ================= fallback (ws too small): f32 gate + direct =================
__global__ __launch_bounds__(64) void gate_fb_kernel(
    const float* __restrict__ z,
    const float* __restrict__ g0_w, const float* __restrict__ g0_b,
    const float* __restrict__ g1_w, const float* __restrict__ g1_b,
    const float* __restrict__ g2_w, const float* __restrict__ g2_b,
    float* __restrict__ coef)
{
    __shared__ float z_s[IN_SZ];
    __shared__ float h0_s[GH];
    __shared__ float h1_s[GH];
    const int b = blockIdx.x;
    const int t = threadIdx.x;
    const float* zr = z + (size_t)b * IN_SZ;
    for (int i = t; i < IN_SZ; i += 64) z_s[i] = zr[i];
    __syncthreads();
    float a0 = g0_b[t];
    for (int i = 0; i < IN_SZ; ++i) a0 = fmaf(z_s[i], g0_w[i * GH + t], a0);
    h0_s[t] = elu_f(a0);
    __syncthreads();
    float a1 = g1_b[t];
    for (int k = 0; k < GH; ++k) a1 = fmaf(h0_s[k], g1_w[k * GH + t], a1);
    h1_s[t] = elu_f(a1);
    __syncthreads();
    if (t < E_NUM) {
        float lg = g2_b[t];
        for (int k = 0; k < GH; ++k) lg = fmaf(h1_s[k], g2_w[k * E_NUM + t], lg);
        float m = lg;
        for (int d = 1; d < 8; d <<= 1) m = fmaxf(m, __shfl_xor(m, d, 8));
        float ex = expf(lg - m);
        float s = ex;
        for (int d = 1; d < 8; d <<= 1) s += __shfl_xor(s, d, 8);
        coef[b * E_NUM + t] = ex / s;
    }
}

__global__ __launch_bounds__(256) void direct_kernel(
    const float* __restrict__ z, const float* __restrict__ w2,
    const float* __restrict__ b2, const float* __restrict__ coef,
    float* __restrict__ out)
{
    __shared__ float z_s[8][IN_SZ];
    __shared__ float c_s[8][E_NUM];
    const int b0 = blockIdx.x * 8;
    const int t  = threadIdx.x;
    for (int idx = t; idx < 8 * IN_SZ; idx += 256)
        ((float*)z_s)[idx] = z[(size_t)b0 * IN_SZ + idx];
    if (t < 64) c_s[t >> 3][t & 7] = coef[b0 * E_NUM + t];
    __syncthreads();
    float outv[8];
    #pragma unroll
    for (int r = 0; r < 8; ++r) outv[r] = 0.0f;
    for (int e = 0; e < E_NUM; ++e) {
        const float* w = w2 + (size_t)e * IN_SZ * OUT_N + t;
        float tmp[8];
        #pragma unroll
        for (int r = 0; r < 8; ++r) tmp[r] = 0.0f;
        #pragma unroll 4
        for (int i = 0; i < IN_SZ; ++i) {
            float wv = w[i * OUT_N];
            #pragma unroll
            for (int r = 0; r < 8; ++r) tmp[r] += z_s[r][i] * wv;
        }
        float bv = b2[e * OUT_N + t];
        #pragma unroll
        for (int r = 0; r < 8; ++r) outv[r] += c_s[r][e] * (tmp[r] + bv);
    }
    #pragma unroll
    for (int r = 0; r < 8; ++r) out[(size_t)(b0 + r) * OUT_N + t] = outv[r];
}

extern "C" void kernel_launch(void* const* d_in, const int* in_sizes, int n_in,
                              void* d_out, int out_size, void* d_ws, size_t ws_size,
                              hipStream_t stream) {
    const float* z    = (const float*)d_in[0];
    const float* g0_w = (const float*)d_in[1];
    const float* g0_b = (const float*)d_in[2];
    const float* g1_w = (const float*)d_in[3];
    const float* g1_b = (const float*)d_in[4];
    const float* g2_w = (const float*)d_in[5];
    const float* g2_b = (const float*)d_in[6];
    // d_in[7..10] = w0,b0,w1,b1 are dead in the reference (layer_out never fed back)
    const float* w2   = (const float*)d_in[11];
    const float* b2   = (const float*)d_in[12];
    float* out = (float*)d_out;

    const size_t w2f_b = (size_t)E_NUM * 16 * NKT * 1024;          // 1.18 MB
    const size_t zf_b  = (size_t)128 * NKT * 1024;                 // 1.18 MB
    const size_t gwf_b = (size_t)GWF_FRAGS * 1024;                 // 47 KB

    char* p = (char*)d_ws;
    ushort* w2f = (ushort*)p;            p += w2f_b;
    ushort* zf  = (ushort*)p;            p += zf_b;
    ushort* gwf = (ushort*)p;

    if (ws_size >= w2f_b + zf_b + gwf_b) {
        prep_kernel<<<W2F_BLKS + ZF_BLKS + GWF_BLKS, 256, 0, stream>>>(
            w2, z, g0_w, g1_w, g2_w, w2f, zf, gwf);
        fused_kernel<<<dim3(B_TOTAL / 32, OUT_N / 16), 128, 0, stream>>>(
            zf, w2f, gwf, g0_b, g1_b, g2_b, b2, out);
    } else {
        float* coef = (float*)d_ws;
        gate_fb_kernel<<<B_TOTAL, 64, 0, stream>>>(z, g0_w, g0_b, g1_w, g1_b,
                                                   g2_w, g2_b, coef);
        direct_kernel<<<B_TOTAL / 8, 256, 0, stream>>>(z, w2, b2, coef, out);
    }
}